// Round 1
// baseline (292.094 us; speedup 1.0000x reference)
//
#include <hip/hip_runtime.h>

#define NNODES 100000
#define NEDGES 1600000
#define BN_EPS 1e-5f
#define L2_EPS 1e-12f

#define BKT_SHIFT 9
#define BKT_SIZE  512
#define NBKT      196            // ceil(100000/512)
#define CHUNK     8192
#define NBLK_E    196            // ceil(1600000/8192)

// ---------------------------------------------------------------------------
// Wave-level block exclusive scan (NT threads, NT/64 waves). 3 barriers total
// (vs 2 per step for the LDS ping-pong version). wsum must hold NT/64 ints.
template<int NT>
__device__ __forceinline__ int block_excl_scan(int v, int* wsum) {
    __syncthreads();                       // protects wsum reuse across calls
    constexpr int NW = NT / 64;
    int incl = v;
#pragma unroll
    for (int off = 1; off < 64; off <<= 1) {
        int t = __shfl_up(incl, off);
        if ((threadIdx.x & 63) >= off) incl += t;
    }
    int wid = threadIdx.x >> 6;
    if ((threadIdx.x & 63) == 63) wsum[wid] = incl;
    __syncthreads();
    if (threadIdx.x < NW) {
        int w = wsum[threadIdx.x];
#pragma unroll
        for (int off = 1; off < NW; off <<= 1) {
            int t = __shfl_up(w, off);
            if ((int)threadIdx.x >= off) w += t;
        }
        wsum[threadIdx.x] = w;             // inclusive wave sums
    }
    __syncthreads();
    int base = wid ? wsum[wid - 1] : 0;
    return base + incl - v;
}

// ---------------------------------------------------------------------------
// Pass 1: per-block bucket histogram (LDS) -> transposed blk_hist (so the
// scan kernel reads coalesced). int4-vectorized edge loads. Block 0 also
// zeroes the BN stats accumulators.
__global__ void hist_kernel(const int* __restrict__ dst,
                            int* __restrict__ blk_hist_T, float* __restrict__ stats) {
    __shared__ int h[NBKT];
    for (int i = threadIdx.x; i < NBKT; i += blockDim.x) h[i] = 0;
    if (blockIdx.x == 0 && threadIdx.x < 128) {
        stats[threadIdx.x] = 0.0f;
        stats[threadIdx.x + 128] = 0.0f;
        stats[threadIdx.x + 256] = 0.0f;
    }
    __syncthreads();
    int base = blockIdx.x * CHUNK;
    int end  = min(base + CHUNK, NEDGES);
    // NEDGES % 4 == 0, base % 4 == 0 -> e < end implies e+3 < end
    for (int e = base + threadIdx.x * 4; e < end; e += blockDim.x * 4) {
        int4 d = *reinterpret_cast<const int4*>(dst + e);
        atomicAdd(&h[d.x >> BKT_SHIFT], 1);
        atomicAdd(&h[d.y >> BKT_SHIFT], 1);
        atomicAdd(&h[d.z >> BKT_SHIFT], 1);
        atomicAdd(&h[d.w >> BKT_SHIFT], 1);
    }
    __syncthreads();
    for (int i = threadIdx.x; i < NBKT; i += blockDim.x)
        blk_hist_T[i * NBLK_E + blockIdx.x] = h[i];   // [bucket][block]
}

// Per-bucket exclusive scan across blocks + bucket totals as by-product.
// Reads the transposed histogram coalesced; shfl-based scan.
__global__ void scan_blocks(const int* __restrict__ blk_hist_T,
                            int* __restrict__ blk_off, int* __restrict__ bucket_total) {
    __shared__ int wsum[4];
    int b = blockIdx.x;
    int i = threadIdx.x;
    int v = (i < NBLK_E) ? blk_hist_T[b * NBLK_E + i] : 0;
    int excl = block_excl_scan<256>(v, wsum);
    if (i < NBLK_E) blk_off[i * NBKT + b] = excl;     // [block][bucket]
    if (i == 255) bucket_total[b] = excl + v;
}

// Exclusive scan of bucket totals -> bucket_base[NBKT+1]
__global__ void scan_buckets(const int* __restrict__ bucket_total, int* __restrict__ bucket_base) {
    __shared__ int wsum[4];
    int i = threadIdx.x;
    int v = (i < NBKT) ? bucket_total[i] : 0;
    int excl = block_excl_scan<256>(v, wsum);
    if (i < NBKT) bucket_base[i] = excl;
    if (i == 255) bucket_base[NBKT] = excl + v;       // == NEDGES
}

// Pass 2: scatter edges into bucket segments (packed dst_local<<23 | src).
// int4-vectorized edge loads; LDS atomics only.
__global__ void bucket_scatter(const int* __restrict__ src, const int* __restrict__ dst,
                               const int* __restrict__ blk_off, const int* __restrict__ bucket_base,
                               unsigned int* __restrict__ staged) {
    __shared__ int cur[NBKT];
    for (int i = threadIdx.x; i < NBKT; i += blockDim.x)
        cur[i] = blk_off[blockIdx.x * NBKT + i] + bucket_base[i];
    __syncthreads();
    int base = blockIdx.x * CHUNK;
    int end  = min(base + CHUNK, NEDGES);
    for (int e = base + threadIdx.x * 4; e < end; e += blockDim.x * 4) {
        int4 d = *reinterpret_cast<const int4*>(dst + e);
        int4 s = *reinterpret_cast<const int4*>(src + e);
        int p0 = atomicAdd(&cur[d.x >> BKT_SHIFT], 1);
        staged[p0] = ((unsigned)(d.x & (BKT_SIZE - 1)) << 23) | (unsigned)s.x;
        int p1 = atomicAdd(&cur[d.y >> BKT_SHIFT], 1);
        staged[p1] = ((unsigned)(d.y & (BKT_SIZE - 1)) << 23) | (unsigned)s.y;
        int p2 = atomicAdd(&cur[d.z >> BKT_SHIFT], 1);
        staged[p2] = ((unsigned)(d.z & (BKT_SIZE - 1)) << 23) | (unsigned)s.z;
        int p3 = atomicAdd(&cur[d.w >> BKT_SHIFT], 1);
        staged[p3] = ((unsigned)(d.w & (BKT_SIZE - 1)) << 23) | (unsigned)s.w;
    }
}

// Pass 3: one block per bucket -> exact CSR (row_ptr + node-sorted col).
__global__ void csr_finalize(const unsigned int* __restrict__ staged,
                             const int* __restrict__ bucket_base,
                             int* __restrict__ row_ptr, int* __restrict__ col) {
    __shared__ int nh[BKT_SIZE];
    __shared__ int cur[BKT_SIZE];
    __shared__ int wsum[8];
    int b = blockIdx.x;
    int beg = bucket_base[b], end = bucket_base[b + 1];

    nh[threadIdx.x] = 0;
    __syncthreads();
    for (int e = beg + threadIdx.x; e < end; e += blockDim.x)
        atomicAdd(&nh[staged[e] >> 23], 1);
    __syncthreads();

    int v = nh[threadIdx.x];
    int excl = block_excl_scan<512>(v, wsum);

    int node = b * BKT_SIZE + threadIdx.x;
    if (node < NNODES) row_ptr[node] = beg + excl;
    if (b == 0 && threadIdx.x == 0) row_ptr[NNODES] = NEDGES;
    cur[threadIdx.x] = excl;
    __syncthreads();

    for (int e = beg + threadIdx.x; e < end; e += blockDim.x) {
        unsigned pk = staged[e];
        int l = (int)(pk >> 23);
        int p = atomicAdd(&cur[l], 1);          // LDS atomic only
        col[beg + p] = (int)(pk & 0x7FFFFF);
    }
}

// ---------------------------------------------------------------------------
// Vector row load: float4 chunks, then float2, then scalar.
template<int CI>
__device__ __forceinline__ void load_row(const float* __restrict__ p, float* r) {
    constexpr int N4 = CI / 4;
#pragma unroll
    for (int i = 0; i < N4; i++) {
        float4 v = ((const float4*)p)[i];
        r[4*i] = v.x; r[4*i+1] = v.y; r[4*i+2] = v.z; r[4*i+3] = v.w;
    }
    if constexpr ((CI % 4) >= 2) {
        float2 v = ((const float2*)(p + 4 * N4))[0];
        r[4*N4] = v.x; r[4*N4+1] = v.y;
    }
    if constexpr ((CI % 2) == 1) r[CI - 1] = p[CI - 1];
}

// ---------------------------------------------------------------------------
// Fused layer, lane-group parallel (G lanes/node), 4-deep gather pipeline,
// LDS weights padded to CI+1 to break power-of-2 bank aliasing.
template<int CI, int SI, int CO, int SO, int G, bool IN_AFFINE, bool DO_STATS>
__global__ void layer_kernel(const int* __restrict__ row_ptr, const int* __restrict__ col,
                             const float* __restrict__ h,
                             const float* __restrict__ ssum_in, const float* __restrict__ ssq_in,
                             const float* __restrict__ g_in, const float* __restrict__ b_in,
                             const float* __restrict__ wl, const float* __restrict__ bl,
                             const float* __restrict__ wr,
                             float* __restrict__ y,
                             float* __restrict__ stat_sum, float* __restrict__ stat_sq) {
    constexpr int NPB = 256 / G;             // nodes per block
    constexpr int OPL = (CO + G - 1) / G;    // outputs per lane
    constexpr int PCI = CI + 1;              // padded LDS stride (bank-conflict fix)

    __shared__ float sWl[CO * PCI];
    __shared__ float sWr[CO * PCI];
    __shared__ float sBl[CO];
    __shared__ float sSc[CI];
    __shared__ float sSh[CI];
    __shared__ float red_sum[CO];
    __shared__ float red_sq[CO];

    for (int i = threadIdx.x; i < CO * CI; i += blockDim.x) {
        int o = i / CI, c = i - o * CI;
        sWl[o * PCI + c] = wl[i];
        sWr[o * PCI + c] = wr[i];
    }
    if (threadIdx.x < CO) {
        sBl[threadIdx.x] = bl[threadIdx.x];
        if (DO_STATS) { red_sum[threadIdx.x] = 0.0f; red_sq[threadIdx.x] = 0.0f; }
    }
    if (IN_AFFINE && threadIdx.x < CI) {
        float m  = ssum_in[threadIdx.x] * (1.0f / NNODES);
        float vv = ssq_in[threadIdx.x] * (1.0f / NNODES) - m * m;
        float s  = g_in[threadIdx.x] / sqrtf(vv + BN_EPS);
        sSc[threadIdx.x] = s;
        sSh[threadIdx.x] = b_in[threadIdx.x] - m * s;
    }
    __syncthreads();

    int node = blockIdx.x * NPB + (threadIdx.x / G);
    int g    = threadIdx.x & (G - 1);
    bool valid = node < NNODES;

    float acc[CI];
#pragma unroll
    for (int c = 0; c < CI; c++) acc[c] = 0.0f;

    int beg = 0, end = 0;
    if (valid) {
        beg = row_ptr[node];
        end = row_ptr[node + 1];
        int j = beg + g;
        // 4 rows in flight
        for (; j + 3 * G < end; j += 4 * G) {
            int i0 = col[j], i1 = col[j + G], i2 = col[j + 2 * G], i3 = col[j + 3 * G];
            float r0[CI], r1[CI], r2[CI], r3[CI];
            load_row<CI>(h + (long)i0 * SI, r0);
            load_row<CI>(h + (long)i1 * SI, r1);
            load_row<CI>(h + (long)i2 * SI, r2);
            load_row<CI>(h + (long)i3 * SI, r3);
#pragma unroll
            for (int c = 0; c < CI; c++) acc[c] += (r0[c] + r1[c]) + (r2[c] + r3[c]);
        }
        // 2 rows in flight
        for (; j + G < end; j += 2 * G) {
            int i0 = col[j], i1 = col[j + G];
            float r0[CI], r1[CI];
            load_row<CI>(h + (long)i0 * SI, r0);
            load_row<CI>(h + (long)i1 * SI, r1);
#pragma unroll
            for (int c = 0; c < CI; c++) acc[c] += r0[c] + r1[c];
        }
        if (j < end) {
            float r0[CI];
            load_row<CI>(h + (long)col[j] * SI, r0);
#pragma unroll
            for (int c = 0; c < CI; c++) acc[c] += r0[c];
        }
    }

    // butterfly: all G lanes end with the full neighbor sum
#pragma unroll
    for (int m = 1; m < G; m <<= 1)
#pragma unroll
        for (int c = 0; c < CI; c++) acc[c] += __shfl_xor(acc[c], m);

    float out[OPL];
    float nrm2 = 0.0f;
    if (valid) {
        float ic = 1.0f / fmaxf((float)(end - beg), 1.0f);
        float xin[CI];
        load_row<CI>(h + (long)node * SI, xin);
        float agg[CI];
#pragma unroll
        for (int c = 0; c < CI; c++) {
            float a  = acc[c] * ic;
            float xv = xin[c];
            if (IN_AFFINE) {
                a  = a  * sSc[c] + sSh[c];
                xv = xv * sSc[c] + sSh[c];
            }
            agg[c] = a;
            xin[c] = xv;
        }
#pragma unroll
        for (int k = 0; k < OPL; k++) {
            int o = g * OPL + k;
            float v = 0.0f;
            if (o < CO) {
                v = sBl[o];
#pragma unroll
                for (int c = 0; c < CI; c++)
                    v += sWl[o * PCI + c] * agg[c] + sWr[o * PCI + c] * xin[c];
            }
            out[k] = v;
            nrm2 += v * v;
        }
    }
#pragma unroll
    for (int m = 1; m < G; m <<= 1) nrm2 += __shfl_xor(nrm2, m);

    if (valid) {
        float inv_nrm = 1.0f / fmaxf(sqrtf(nrm2), L2_EPS);
#pragma unroll
        for (int k = 0; k < OPL; k++) {
            int o = g * OPL + k;
            if (o < CO) {
                float v = fmaxf(out[k] * inv_nrm, 0.0f);   // L2 norm + ReLU
                y[(long)node * SO + o] = v;
                if (DO_STATS) {
                    atomicAdd(&red_sum[o], v);
                    atomicAdd(&red_sq[o], v * v);
                }
            }
        }
    }

    if (DO_STATS) {
        __syncthreads();
        if (threadIdx.x < CO) {
            atomicAdd(&stat_sum[threadIdx.x], red_sum[threadIdx.x]);
            atomicAdd(&stat_sq[threadIdx.x], red_sq[threadIdx.x]);
        }
    }
}

// ---------------------------------------------------------------------------
extern "C" void kernel_launch(void* const* d_in, const int* in_sizes, int n_in,
                              void* d_out, int out_size, void* d_ws, size_t ws_size,
                              hipStream_t stream) {
    const float* x   = (const float*)d_in[0];
    const int*   ei  = (const int*)d_in[1];
    const int*   src = ei;
    const int*   dst = ei + NEDGES;

    const float* w1l = (const float*)d_in[2];
    const float* b1l = (const float*)d_in[3];
    const float* w1r = (const float*)d_in[4];
    const float* w2l = (const float*)d_in[5];
    const float* b2l = (const float*)d_in[6];
    const float* w2r = (const float*)d_in[7];
    const float* w3l = (const float*)d_in[8];
    const float* b3l = (const float*)d_in[9];
    const float* w3r = (const float*)d_in[10];
    const float* w4l = (const float*)d_in[11];
    const float* b4l = (const float*)d_in[12];
    const float* w4r = (const float*)d_in[13];
    const float* g1  = (const float*)d_in[14];
    const float* be1 = (const float*)d_in[15];
    const float* g2  = (const float*)d_in[16];
    const float* be2 = (const float*)d_in[17];
    const float* g3  = (const float*)d_in[18];
    const float* be3 = (const float*)d_in[19];

    char* w = (char*)d_ws;
    int* blk_hist     = (int*)w;  w += NBLK_E * NBKT * 4;
    int* blk_off      = (int*)w;  w += NBLK_E * NBKT * 4;
    int* bucket_total = (int*)w;  w += 256 * 4;
    int* bucket_base  = (int*)w;  w += 256 * 4;
    int* row_ptr      = (int*)w;  w += (NNODES + 8) * 4;
    int* col          = (int*)w;  w += NEDGES * 4;
    float* hA         = (float*)w; w += NNODES * 16 * 4;
    float* hB         = (float*)w; w += NNODES * 16 * 4;   // aliased by staged
    float* stats      = (float*)w; w += 3 * 128 * 4;
    unsigned int* staged = (unsigned int*)hB;  // dead before hB is written

    float* ssum1 = stats + 0 * 128, *ssq1 = ssum1 + 32;
    float* ssum2 = stats + 1 * 128, *ssq2 = ssum2 + 32;
    float* ssum3 = stats + 2 * 128, *ssq3 = ssum3 + 32;

    // atomic-free CSR build (LDS atomics only)
    hist_kernel   <<<NBLK_E, 512, 0, stream>>>(dst, blk_hist, stats);
    scan_blocks   <<<NBKT, 256, 0, stream>>>(blk_hist, blk_off, bucket_total);
    scan_buckets  <<<1, 256, 0, stream>>>(bucket_total, bucket_base);
    bucket_scatter<<<NBLK_E, 512, 0, stream>>>(src, dst, blk_off, bucket_base, staged);
    csr_finalize  <<<NBKT, 512, 0, stream>>>(staged, bucket_base, row_ptr, col);

    // layer 1: 4 -> 6 (stride 4 -> 8), G=4, +stats
    layer_kernel<4, 4, 6, 8, 4, false, true><<<(NNODES * 4 + 255) / 256, 256, 0, stream>>>(
        row_ptr, col, x, nullptr, nullptr, nullptr, nullptr,
        w1l, b1l, w1r, hA, ssum1, ssq1);

    // layer 2: 6 -> 8 (stride 8 -> 8), G=4, BN1 derived in-block, +stats
    layer_kernel<6, 8, 8, 8, 4, true, true><<<(NNODES * 4 + 255) / 256, 256, 0, stream>>>(
        row_ptr, col, hA, ssum1, ssq1, g1, be1,
        w2l, b2l, w2r, hB, ssum2, ssq2);

    // layer 3: 8 -> 16 (stride 8 -> 16), G=4, BN2 derived, +stats
    layer_kernel<8, 8, 16, 16, 4, true, true><<<(NNODES * 4 + 255) / 256, 256, 0, stream>>>(
        row_ptr, col, hB, ssum2, ssq2, g2, be2,
        w3l, b3l, w3r, hA, ssum3, ssq3);

    // layer 4: 16 -> 32 (stride 16 -> 32), G=8, BN3 derived, ReLU -> d_out
    layer_kernel<16, 16, 32, 32, 8, true, false><<<(NNODES * 8 + 255) / 256, 256, 0, stream>>>(
        row_ptr, col, hA, ssum3, ssq3, g3, be3,
        w4l, b4l, w4r, (float*)d_out, nullptr, nullptr);
}

// Round 2
// 259.950 us; speedup vs baseline: 1.1237x; 1.1237x over previous
//
#include <hip/hip_runtime.h>

#define NNODES 100000
#define NEDGES 1600000
#define BN_EPS 1e-5f
#define L2_EPS 1e-12f

#define BKT_SHIFT 9
#define BKT_SIZE  512
#define NBKT      196            // ceil(100000/512)
#define CHUNK     8192
#define NBLK_E    196            // ceil(1600000/8192)
#define NSLOT     64             // BN-stats shard count

// ---------------------------------------------------------------------------
// Wave-level block exclusive scan (NT threads, NT/64 waves). Leading barrier
// protects wsum reuse across consecutive calls.
template<int NT>
__device__ __forceinline__ int block_excl_scan(int v, int* wsum) {
    __syncthreads();
    constexpr int NW = NT / 64;
    int incl = v;
#pragma unroll
    for (int off = 1; off < 64; off <<= 1) {
        int t = __shfl_up(incl, off);
        if ((threadIdx.x & 63) >= off) incl += t;
    }
    int wid = threadIdx.x >> 6;
    if ((threadIdx.x & 63) == 63) wsum[wid] = incl;
    __syncthreads();
    if (threadIdx.x < NW) {
        int w = wsum[threadIdx.x];
#pragma unroll
        for (int off = 1; off < NW; off <<= 1) {
            int t = __shfl_up(w, off);
            if ((int)threadIdx.x >= off) w += t;
        }
        wsum[threadIdx.x] = w;             // inclusive wave sums
    }
    __syncthreads();
    int base = wid ? wsum[wid - 1] : 0;
    return base + incl - v;
}

// ---------------------------------------------------------------------------
// Pass 1: per-block bucket histogram (LDS) -> transposed blk_hist. Block 0
// also zeroes the sharded BN stats accumulators.
__global__ void hist_kernel(const int* __restrict__ dst,
                            int* __restrict__ blk_hist_T, float* __restrict__ stats) {
    __shared__ int h[NBKT];
    for (int i = threadIdx.x; i < NBKT; i += blockDim.x) h[i] = 0;
    if (blockIdx.x == 0)
        for (int i = threadIdx.x; i < 3 * NSLOT * 64; i += blockDim.x) stats[i] = 0.0f;
    __syncthreads();
    int base = blockIdx.x * CHUNK;
    int end  = min(base + CHUNK, NEDGES);
    // NEDGES % 4 == 0, base % 4 == 0 -> e < end implies e+3 < end
    for (int e = base + threadIdx.x * 4; e < end; e += blockDim.x * 4) {
        int4 d = *reinterpret_cast<const int4*>(dst + e);
        atomicAdd(&h[d.x >> BKT_SHIFT], 1);
        atomicAdd(&h[d.y >> BKT_SHIFT], 1);
        atomicAdd(&h[d.z >> BKT_SHIFT], 1);
        atomicAdd(&h[d.w >> BKT_SHIFT], 1);
    }
    __syncthreads();
    for (int i = threadIdx.x; i < NBKT; i += blockDim.x)
        blk_hist_T[i * NBLK_E + blockIdx.x] = h[i];   // [bucket][block]
}

// Per-bucket exclusive scan across blocks + bucket totals as by-product.
__global__ void scan_blocks(const int* __restrict__ blk_hist_T,
                            int* __restrict__ blk_off, int* __restrict__ bucket_total) {
    __shared__ int wsum[4];
    int b = blockIdx.x;
    int i = threadIdx.x;
    int v = (i < NBLK_E) ? blk_hist_T[b * NBLK_E + i] : 0;
    int excl = block_excl_scan<256>(v, wsum);
    if (i < NBLK_E) blk_off[i * NBKT + b] = excl;     // [block][bucket]
    if (i == 255) bucket_total[b] = excl + v;
}

// Pass 2: scatter edges into bucket segments (packed dst_local<<23 | src).
// Bucket bases derived in-block from bucket_total (kills a kernel launch).
__global__ void bucket_scatter(const int* __restrict__ src, const int* __restrict__ dst,
                               const int* __restrict__ blk_off, const int* __restrict__ bucket_total,
                               unsigned int* __restrict__ staged) {
    __shared__ int cur[NBKT];
    __shared__ int wsum[8];
    int v = (threadIdx.x < NBKT) ? bucket_total[threadIdx.x] : 0;
    int bbase = block_excl_scan<512>(v, wsum);
    if (threadIdx.x < NBKT)
        cur[threadIdx.x] = bbase + blk_off[blockIdx.x * NBKT + threadIdx.x];
    __syncthreads();
    int base = blockIdx.x * CHUNK;
    int end  = min(base + CHUNK, NEDGES);
    for (int e = base + threadIdx.x * 4; e < end; e += blockDim.x * 4) {
        int4 d = *reinterpret_cast<const int4*>(dst + e);
        int4 s = *reinterpret_cast<const int4*>(src + e);
        int p0 = atomicAdd(&cur[d.x >> BKT_SHIFT], 1);
        staged[p0] = ((unsigned)(d.x & (BKT_SIZE - 1)) << 23) | (unsigned)s.x;
        int p1 = atomicAdd(&cur[d.y >> BKT_SHIFT], 1);
        staged[p1] = ((unsigned)(d.y & (BKT_SIZE - 1)) << 23) | (unsigned)s.y;
        int p2 = atomicAdd(&cur[d.z >> BKT_SHIFT], 1);
        staged[p2] = ((unsigned)(d.z & (BKT_SIZE - 1)) << 23) | (unsigned)s.z;
        int p3 = atomicAdd(&cur[d.w >> BKT_SHIFT], 1);
        staged[p3] = ((unsigned)(d.w & (BKT_SIZE - 1)) << 23) | (unsigned)s.w;
    }
}

// Pass 3: one block per bucket -> exact CSR (row_ptr + node-sorted col).
// Bucket range derived in-block from bucket_total.
__global__ void csr_finalize(const unsigned int* __restrict__ staged,
                             const int* __restrict__ bucket_total,
                             int* __restrict__ row_ptr, int* __restrict__ col) {
    __shared__ int nh[BKT_SIZE];
    __shared__ int cur[BKT_SIZE];
    __shared__ int wsum[8];
    __shared__ int sBeg, sEnd;
    int b = blockIdx.x;

    nh[threadIdx.x] = 0;                      // covered by scan's leading barrier
    int v = (threadIdx.x < NBKT) ? bucket_total[threadIdx.x] : 0;
    int excl = block_excl_scan<512>(v, wsum);
    if (threadIdx.x == b) { sBeg = excl; sEnd = excl + v; }
    __syncthreads();
    int beg = sBeg, end = sEnd;

    for (int e = beg + threadIdx.x; e < end; e += blockDim.x)
        atomicAdd(&nh[staged[e] >> 23], 1);
    __syncthreads();

    int hv = nh[threadIdx.x];
    int hexcl = block_excl_scan<512>(hv, wsum);

    int node = b * BKT_SIZE + threadIdx.x;
    if (node < NNODES) row_ptr[node] = beg + hexcl;
    if (b == 0 && threadIdx.x == 0) row_ptr[NNODES] = NEDGES;
    cur[threadIdx.x] = hexcl;
    __syncthreads();

    for (int e = beg + threadIdx.x; e < end; e += blockDim.x) {
        unsigned pk = staged[e];
        int l = (int)(pk >> 23);
        int p = atomicAdd(&cur[l], 1);          // LDS atomic only
        col[beg + p] = (int)(pk & 0x7FFFFF);
    }
}

// ---------------------------------------------------------------------------
// Vector row load: float4 chunks, then float2, then scalar.
template<int CI>
__device__ __forceinline__ void load_row(const float* __restrict__ p, float* r) {
    constexpr int N4 = CI / 4;
#pragma unroll
    for (int i = 0; i < N4; i++) {
        float4 v = ((const float4*)p)[i];
        r[4*i] = v.x; r[4*i+1] = v.y; r[4*i+2] = v.z; r[4*i+3] = v.w;
    }
    if constexpr ((CI % 4) >= 2) {
        float2 v = ((const float2*)(p + 4 * N4))[0];
        r[4*N4] = v.x; r[4*N4+1] = v.y;
    }
    if constexpr ((CI % 2) == 1) r[CI - 1] = p[CI - 1];
}

// ---------------------------------------------------------------------------
// Fused layer, lane-group parallel (G lanes/node). BN stats sharded across
// NSLOT global slots (low atomic contention); prologue re-reduces the shards.
template<int CI, int SI, int CO, int SO, int G, bool IN_AFFINE, bool DO_STATS>
__global__ void layer_kernel(const int* __restrict__ row_ptr, const int* __restrict__ col,
                             const float* __restrict__ h,
                             const float* __restrict__ ssum_in, const float* __restrict__ ssq_in,
                             const float* __restrict__ g_in, const float* __restrict__ b_in,
                             const float* __restrict__ wl, const float* __restrict__ bl,
                             const float* __restrict__ wr,
                             float* __restrict__ y,
                             float* __restrict__ stat_sum, float* __restrict__ stat_sq) {
    constexpr int NPB = 256 / G;             // nodes per block
    constexpr int OPL = (CO + G - 1) / G;    // outputs per lane
    constexpr int PCI = CI + 1;              // padded LDS stride (bank-conflict fix)

    __shared__ float sWl[CO * PCI];
    __shared__ float sWr[CO * PCI];
    __shared__ float sBl[CO];
    __shared__ float sSc[CI];
    __shared__ float sSh[CI];
    __shared__ float sSumR[CI];
    __shared__ float sSqR[CI];
    __shared__ float red_sum[CO];
    __shared__ float red_sq[CO];

    for (int i = threadIdx.x; i < CO * CI; i += blockDim.x) {
        int o = i / CI, c = i - o * CI;
        sWl[o * PCI + c] = wl[i];
        sWr[o * PCI + c] = wr[i];
    }
    if (threadIdx.x < CO) {
        sBl[threadIdx.x] = bl[threadIdx.x];
        if (DO_STATS) { red_sum[threadIdx.x] = 0.0f; red_sq[threadIdx.x] = 0.0f; }
    }
    if (IN_AFFINE && threadIdx.x < CI) { sSumR[threadIdx.x] = 0.0f; sSqR[threadIdx.x] = 0.0f; }
    __syncthreads();
    if (IN_AFFINE) {
        int c = threadIdx.x & 31, sl = threadIdx.x >> 5;    // 8 slices over NSLOT
        if (c < CI) {
            float ps = 0.0f, pq = 0.0f;
#pragma unroll
            for (int s = sl; s < NSLOT; s += 8) {
                ps += ssum_in[s * 64 + c];
                pq += ssq_in[s * 64 + c];
            }
            atomicAdd(&sSumR[c], ps);
            atomicAdd(&sSqR[c], pq);
        }
        __syncthreads();
        if (threadIdx.x < CI) {
            float m  = sSumR[threadIdx.x] * (1.0f / NNODES);
            float vv = sSqR[threadIdx.x] * (1.0f / NNODES) - m * m;
            float s  = g_in[threadIdx.x] / sqrtf(vv + BN_EPS);
            sSc[threadIdx.x] = s;
            sSh[threadIdx.x] = b_in[threadIdx.x] - m * s;
        }
    }
    __syncthreads();

    int node = blockIdx.x * NPB + (threadIdx.x / G);
    int g    = threadIdx.x & (G - 1);
    bool valid = node < NNODES;

    float acc[CI];
#pragma unroll
    for (int c = 0; c < CI; c++) acc[c] = 0.0f;

    int beg = 0, end = 0;
    if (valid) {
        beg = row_ptr[node];
        end = row_ptr[node + 1];
        int j = beg + g;
        if constexpr (G <= 8) {
            // 4 rows in flight
            for (; j + 3 * G < end; j += 4 * G) {
                int i0 = col[j], i1 = col[j + G], i2 = col[j + 2 * G], i3 = col[j + 3 * G];
                float r0[CI], r1[CI], r2[CI], r3[CI];
                load_row<CI>(h + (long)i0 * SI, r0);
                load_row<CI>(h + (long)i1 * SI, r1);
                load_row<CI>(h + (long)i2 * SI, r2);
                load_row<CI>(h + (long)i3 * SI, r3);
#pragma unroll
                for (int c = 0; c < CI; c++) acc[c] += (r0[c] + r1[c]) + (r2[c] + r3[c]);
            }
        }
        // 2 rows in flight
        for (; j + G < end; j += 2 * G) {
            int i0 = col[j], i1 = col[j + G];
            float r0[CI], r1[CI];
            load_row<CI>(h + (long)i0 * SI, r0);
            load_row<CI>(h + (long)i1 * SI, r1);
#pragma unroll
            for (int c = 0; c < CI; c++) acc[c] += r0[c] + r1[c];
        }
        if (j < end) {
            float r0[CI];
            load_row<CI>(h + (long)col[j] * SI, r0);
#pragma unroll
            for (int c = 0; c < CI; c++) acc[c] += r0[c];
        }
    }

    // butterfly: all G lanes end with the full neighbor sum
#pragma unroll
    for (int m = 1; m < G; m <<= 1)
#pragma unroll
        for (int c = 0; c < CI; c++) acc[c] += __shfl_xor(acc[c], m);

    float out[OPL];
    float nrm2 = 0.0f;
    if (valid) {
        float ic = 1.0f / fmaxf((float)(end - beg), 1.0f);
        float xin[CI];
        load_row<CI>(h + (long)node * SI, xin);
        float agg[CI];
#pragma unroll
        for (int c = 0; c < CI; c++) {
            float a  = acc[c] * ic;
            float xv = xin[c];
            if (IN_AFFINE) {
                a  = a  * sSc[c] + sSh[c];
                xv = xv * sSc[c] + sSh[c];
            }
            agg[c] = a;
            xin[c] = xv;
        }
#pragma unroll
        for (int k = 0; k < OPL; k++) {
            int o = g * OPL + k;
            float v = 0.0f;
            if (o < CO) {
                v = sBl[o];
#pragma unroll
                for (int c = 0; c < CI; c++)
                    v += sWl[o * PCI + c] * agg[c] + sWr[o * PCI + c] * xin[c];
            }
            out[k] = v;
            nrm2 += v * v;
        }
    }
#pragma unroll
    for (int m = 1; m < G; m <<= 1) nrm2 += __shfl_xor(nrm2, m);

    if (valid) {
        float inv_nrm = 1.0f / fmaxf(sqrtf(nrm2), L2_EPS);
#pragma unroll
        for (int k = 0; k < OPL; k++) {
            int o = g * OPL + k;
            if (o < CO) {
                float v = fmaxf(out[k] * inv_nrm, 0.0f);   // L2 norm + ReLU
                y[(long)node * SO + o] = v;
                if (DO_STATS) {
                    atomicAdd(&red_sum[o], v);
                    atomicAdd(&red_sq[o], v * v);
                }
            }
        }
    }

    if (DO_STATS) {
        __syncthreads();
        if (threadIdx.x < CO) {
            int slot = blockIdx.x & (NSLOT - 1);
            atomicAdd(&stat_sum[slot * 64 + threadIdx.x], red_sum[threadIdx.x]);
            atomicAdd(&stat_sq [slot * 64 + threadIdx.x], red_sq[threadIdx.x]);
        }
    }
}

// ---------------------------------------------------------------------------
extern "C" void kernel_launch(void* const* d_in, const int* in_sizes, int n_in,
                              void* d_out, int out_size, void* d_ws, size_t ws_size,
                              hipStream_t stream) {
    const float* x   = (const float*)d_in[0];
    const int*   ei  = (const int*)d_in[1];
    const int*   src = ei;
    const int*   dst = ei + NEDGES;

    const float* w1l = (const float*)d_in[2];
    const float* b1l = (const float*)d_in[3];
    const float* w1r = (const float*)d_in[4];
    const float* w2l = (const float*)d_in[5];
    const float* b2l = (const float*)d_in[6];
    const float* w2r = (const float*)d_in[7];
    const float* w3l = (const float*)d_in[8];
    const float* b3l = (const float*)d_in[9];
    const float* w3r = (const float*)d_in[10];
    const float* w4l = (const float*)d_in[11];
    const float* b4l = (const float*)d_in[12];
    const float* w4r = (const float*)d_in[13];
    const float* g1  = (const float*)d_in[14];
    const float* be1 = (const float*)d_in[15];
    const float* g2  = (const float*)d_in[16];
    const float* be2 = (const float*)d_in[17];
    const float* g3  = (const float*)d_in[18];
    const float* be3 = (const float*)d_in[19];

    char* w = (char*)d_ws;
    int* blk_hist     = (int*)w;  w += NBLK_E * NBKT * 4;
    int* blk_off      = (int*)w;  w += NBLK_E * NBKT * 4;
    int* bucket_total = (int*)w;  w += 256 * 4;
    int* row_ptr      = (int*)w;  w += (NNODES + 8) * 4;
    int* col          = (int*)w;  w += NEDGES * 4;
    float* hA         = (float*)w; w += NNODES * 16 * 4;
    float* hB         = (float*)w; w += NNODES * 16 * 4;   // aliased by staged
    float* stats      = (float*)w; w += 3 * NSLOT * 64 * 4;
    unsigned int* staged = (unsigned int*)hB;  // dead before hB is written

    float* ssum1 = stats + 0 * NSLOT * 64, *ssq1 = ssum1 + 32;
    float* ssum2 = stats + 1 * NSLOT * 64, *ssq2 = ssum2 + 32;
    float* ssum3 = stats + 2 * NSLOT * 64, *ssq3 = ssum3 + 32;

    // atomic-free CSR build (LDS atomics only), 4 launches
    hist_kernel   <<<NBLK_E, 512, 0, stream>>>(dst, blk_hist, stats);
    scan_blocks   <<<NBKT, 256, 0, stream>>>(blk_hist, blk_off, bucket_total);
    bucket_scatter<<<NBLK_E, 512, 0, stream>>>(src, dst, blk_off, bucket_total, staged);
    csr_finalize  <<<NBKT, 512, 0, stream>>>(staged, bucket_total, row_ptr, col);

    // layer 1: 4 -> 6 (stride 4 -> 8), G=8, +stats
    layer_kernel<4, 4, 6, 8, 8, false, true><<<(NNODES * 8 + 255) / 256, 256, 0, stream>>>(
        row_ptr, col, x, nullptr, nullptr, nullptr, nullptr,
        w1l, b1l, w1r, hA, ssum1, ssq1);

    // layer 2: 6 -> 8 (stride 8 -> 8), G=8, BN1 derived in-block, +stats
    layer_kernel<6, 8, 8, 8, 8, true, true><<<(NNODES * 8 + 255) / 256, 256, 0, stream>>>(
        row_ptr, col, hA, ssum1, ssq1, g1, be1,
        w2l, b2l, w2r, hB, ssum2, ssq2);

    // layer 3: 8 -> 16 (stride 8 -> 16), G=8, BN2 derived, +stats
    layer_kernel<8, 8, 16, 16, 8, true, true><<<(NNODES * 8 + 255) / 256, 256, 0, stream>>>(
        row_ptr, col, hB, ssum2, ssq2, g2, be2,
        w3l, b3l, w3r, hA, ssum3, ssq3);

    // layer 4: 16 -> 32 (stride 16 -> 32), G=16, BN3 derived, ReLU -> d_out
    layer_kernel<16, 16, 32, 32, 16, true, false><<<(NNODES * 16 + 255) / 256, 256, 0, stream>>>(
        row_ptr, col, hA, ssum3, ssq3, g3, be3,
        w4l, b4l, w4r, (float*)d_out, nullptr, nullptr);
}